// Round 3
// baseline (411.267 us; speedup 1.0000x reference)
//
#include <hip/hip_runtime.h>
#include <hip/hip_cooperative_groups.h>

namespace cg = cooperative_groups;

#define N_TERMS 2048
#define NCOL 4096
#define NC4 1024                       // float4 per row
#define NCHUNK 128
#define RPC (N_TERMS / NCHUNK)         // 16 rows per chunk
#define NBLK 512
#define NTHR 256

// One cooperative kernel, 512 blocks x 256 threads (2 blocks/CU -> guaranteed
// co-resident; tiny VGPR/LDS footprint).
//
// P1: partial column |x| sums, chunk-major [NCHUNK][NCOL] in ws.
// P2a: blocks 0..15 reduce 128 partials/column, compute lam/delta, write out
//      row 0 (center) + per-column scale/dhalf/crossflag.
// P2b: block 0: exclusive prefix sum of crossflag -> tail row target per col.
// P3: all blocks grid-stride write rows 1..6143.
__global__ void __launch_bounds__(NTHR, 2)
k_fused(const float* __restrict__ x, float* __restrict__ out, float* __restrict__ ws) {
    float* partial   = ws;                        // 128*4096 floats = 2 MB
    float* scale     = partial + NCHUNK * NCOL;   // 4096
    float* dhalf     = scale + NCOL;              // 4096
    int*   crossflag = (int*)(dhalf + NCOL);      // 4096
    int*   rowtarget = crossflag + NCOL;          // 4096

    cg::grid_group grid = cg::this_grid();
    const int b = blockIdx.x;
    const int t = threadIdx.x;
    const float4* x4 = (const float4*)x;

    // ---------------- P1: partial |x| sums ----------------
    {
        int chunk = b >> 2;            // [0,128)
        int col4  = (b & 3) * NTHR + t;  // [0,1024)
        int r0 = chunk * RPC;
        int r1 = r0 + RPC;
        if (r0 == 0) r0 = 1;           // center row excluded from abs_sum
        float4 acc = {0.f, 0.f, 0.f, 0.f};
#pragma unroll
        for (int r = r0; r < r1; ++r) {
            float4 v = x4[(long)r * NC4 + col4];
            acc.x += fabsf(v.x);
            acc.y += fabsf(v.y);
            acc.z += fabsf(v.z);
            acc.w += fabsf(v.w);
        }
        ((float4*)partial)[chunk * NC4 + col4] = acc;
    }
    __threadfence();
    grid.sync();

    // ---------------- P2a: per-column stats (blocks 0..15) ----------------
    if (b < 16) {
        int c = b * NTHR + t;          // [0,4096)
        float s0 = 0.f, s1 = 0.f, s2 = 0.f, s3 = 0.f;
#pragma unroll 4
        for (int k = 0; k < NCHUNK; k += 4) {
            s0 += partial[(k + 0) * NCOL + c];
            s1 += partial[(k + 1) * NCOL + c];
            s2 += partial[(k + 2) * NCOL + c];
            s3 += partial[(k + 3) * NCOL + c];
        }
        float s = (s0 + s1) + (s2 + s3);
        float x0 = x[c];
        float u = x0 + s;
        float l = x0 - s;
        bool cross = (l * u) < 0.0f;
        bool pos = (l >= 0.0f);
        float denom = u - l;
        float lam = (pos ? 1.0f : 0.0f) +
                    (cross ? ((denom != 0.0f) ? u / denom : 0.5f) : 0.0f);
        float delta = fmaxf(-lam * l, (1.0f - lam) * u);
        float crossf = cross ? 1.0f : 0.0f;
        float posf = pos ? 1.0f : 0.0f;
        out[c] = (delta * 0.5f + lam * x0) * crossf + x0 * posf;  // row 0
        scale[c] = lam * crossf + posf;
        dhalf[c] = delta * 0.5f * crossf;
        crossflag[c] = cross ? 1 : 0;
    }
    __threadfence();
    grid.sync();

    // ---------------- P2b: prefix scan (block 0) ----------------
    __shared__ int tsum[NTHR];
    if (b == 0) {
        const int PER = NCOL / NTHR;   // 16
        int base = t * PER;
        int ex[PER];
        int run = 0;
#pragma unroll
        for (int i = 0; i < PER; ++i) {
            ex[i] = run;
            run += crossflag[base + i];
        }
        tsum[t] = run;
        __syncthreads();
        for (int off = 1; off < NTHR; off <<= 1) {
            int v = 0;
            if (t >= off) v = tsum[t - off];
            __syncthreads();
            tsum[t] += v;
            __syncthreads();
        }
        int excl = (t == 0) ? 0 : tsum[t - 1];
#pragma unroll
        for (int i = 0; i < PER; ++i) rowtarget[base + i] = N_TERMS + excl + ex[i];
    }
    __threadfence();
    grid.sync();

    // ---------------- P3: write rows 1..6143 ----------------
    const long total4 = (long)(N_TERMS + NCOL - 1) * NC4;  // 6143*1024
    float4* o4 = (float4*)out;
    for (long g = (long)b * NTHR + t; g < total4; g += (long)NBLK * NTHR) {
        int row  = (int)(g >> 10) + 1;
        int col4 = (int)(g & 1023);
        if (row < N_TERMS) {
            float4 v = x4[(long)row * NC4 + col4];
            float4 sc = ((const float4*)scale)[col4];
            v.x *= sc.x; v.y *= sc.y; v.z *= sc.z; v.w *= sc.w;
            o4[(long)row * NC4 + col4] = v;
        } else {
            int4 rt = ((const int4*)rowtarget)[col4];
            float4 dh = ((const float4*)dhalf)[col4];
            float4 v;
            v.x = (rt.x == row) ? dh.x : 0.0f;
            v.y = (rt.y == row) ? dh.y : 0.0f;
            v.z = (rt.z == row) ? dh.z : 0.0f;
            v.w = (rt.w == row) ? dh.w : 0.0f;
            o4[(long)row * NC4 + col4] = v;
        }
    }
}

extern "C" void kernel_launch(void* const* d_in, const int* in_sizes, int n_in,
                              void* d_out, int out_size, void* d_ws, size_t ws_size,
                              hipStream_t stream) {
    const float* x = (const float*)d_in[0];
    float* out = (float*)d_out;
    float* ws = (float*)d_ws;

    void* args[] = {(void*)&x, (void*)&out, (void*)&ws};
    hipLaunchCooperativeKernel((const void*)k_fused, dim3(NBLK), dim3(NTHR),
                               args, 0, stream);
}

// Round 5
// 142.598 us; speedup vs baseline: 2.8841x; 2.8841x over previous
//
#include <hip/hip_runtime.h>

#define N_TERMS 2048
#define NCOL 4096
#define NC4 1024                           // float4 per row
#define NCHUNK 128
#define RPC (N_TERMS / NCHUNK)             // 16 rows per chunk

typedef float f4_t __attribute__((ext_vector_type(4)));

// ---------------------------------------------------------------------------
// Kernel 1: partial column-wise |x| sums over row chunks (skipping row 0).
// grid (4, 128) = 512 blocks -> 2 blocks/CU, 16 independent float4 loads per
// thread. Also zeroes the done-counter used by kernel 2 (stream order makes
// this race-free). partial is chunk-major [NCHUNK][NCOL].
// ---------------------------------------------------------------------------
__global__ void k_partial_abs(const float* __restrict__ x, float* __restrict__ partial,
                              int* __restrict__ counter) {
    if (blockIdx.x == 0 && blockIdx.y == 0 && threadIdx.x == 0) *counter = 0;
    int col4 = blockIdx.x * blockDim.x + threadIdx.x;  // [0, 1024)
    int chunk = blockIdx.y;
    int r0 = chunk * RPC;
    int r1 = r0 + RPC;
    if (r0 == 0) r0 = 1;  // center row excluded from abs_sum
    const f4_t* x4 = (const f4_t*)x;
    f4_t acc = {0.f, 0.f, 0.f, 0.f};
#pragma unroll
    for (int r = r0; r < r1; ++r) {
        f4_t v = x4[(long)r * NC4 + col4];
        acc.x += fabsf(v.x);
        acc.y += fabsf(v.y);
        acc.z += fabsf(v.z);
        acc.w += fabsf(v.w);
    }
    ((f4_t*)partial)[chunk * NC4 + col4] = acc;
}

// ---------------------------------------------------------------------------
// Kernel 2: per-column stats + inline prefix scan.
// 16 blocks x 256 threads. Each block handles 256 columns: reduce 128
// partials, compute lam/delta, write output row 0 + scale/dhalf/crossflag.
// The last block to finish (atomic ticket 15) performs the 4096-wide
// exclusive prefix sum of crossflag -> rowtarget, saving a third dispatch.
// ---------------------------------------------------------------------------
__global__ void k_stats(const float* __restrict__ x, const float* __restrict__ partial,
                        float* __restrict__ out0, float* __restrict__ scale,
                        float* __restrict__ dhalf, int* __restrict__ crossflag,
                        int* __restrict__ rowtarget, int* __restrict__ counter) {
    const int t = threadIdx.x;
    int c = blockIdx.x * blockDim.x + t;
    float s0 = 0.f, s1 = 0.f, s2 = 0.f, s3 = 0.f;
#pragma unroll 4
    for (int k = 0; k < NCHUNK; k += 4) {
        s0 += partial[(k + 0) * NCOL + c];
        s1 += partial[(k + 1) * NCOL + c];
        s2 += partial[(k + 2) * NCOL + c];
        s3 += partial[(k + 3) * NCOL + c];
    }
    float s = (s0 + s1) + (s2 + s3);
    float x0 = x[c];
    float u = x0 + s;
    float l = x0 - s;
    bool cross = (l * u) < 0.0f;
    bool pos = (l >= 0.0f);
    float denom = u - l;
    float lam = (pos ? 1.0f : 0.0f) +
                (cross ? ((denom != 0.0f) ? u / denom : 0.5f) : 0.0f);
    float delta = fmaxf(-lam * l, (1.0f - lam) * u);
    float crossf = cross ? 1.0f : 0.0f;
    float posf = pos ? 1.0f : 0.0f;
    out0[c] = (delta * 0.5f + lam * x0) * crossf + x0 * posf;  // output row 0
    scale[c] = lam * crossf + posf;
    dhalf[c] = delta * 0.5f * crossf;
    crossflag[c] = cross ? 1 : 0;

    // --- last-done block performs the scan ---
    __shared__ int ticket;
    __threadfence();  // release our crossflag stores (device scope)
    __syncthreads();
    if (t == 0)
        ticket = __hip_atomic_fetch_add(counter, 1, __ATOMIC_ACQ_REL,
                                        __HIP_MEMORY_SCOPE_AGENT);
    __syncthreads();
    if (ticket == 15) {
        __threadfence();  // acquire side: order counter read before crossflag reads
        const int PER = NCOL / 256;  // 16
        __shared__ int tsum[256];
        int base = t * PER;
        int ex[PER];
        int run = 0;
#pragma unroll
        for (int i = 0; i < PER; ++i) {
            ex[i] = run;
            run += __hip_atomic_load(&crossflag[base + i], __ATOMIC_RELAXED,
                                     __HIP_MEMORY_SCOPE_AGENT);
        }
        tsum[t] = run;
        __syncthreads();
        for (int off = 1; off < 256; off <<= 1) {
            int v = 0;
            if (t >= off) v = tsum[t - off];
            __syncthreads();
            tsum[t] += v;
            __syncthreads();
        }
        int excl = (t == 0) ? 0 : tsum[t - 1];
#pragma unroll
        for (int i = 0; i < PER; ++i) rowtarget[base + i] = N_TERMS + excl + ex[i];
    }
}

// ---------------------------------------------------------------------------
// Kernel 3: write rows 1..6143. Rows 1..2047: gens = x * scale[col].
// Rows 2048..6143: dhalf[col] on the (rowtarget[col]==row) slot, else 0.
// Nontemporal stores: output is never re-read, keep L2 clean for x/scale.
// ---------------------------------------------------------------------------
__global__ void k_write(const float* __restrict__ x, const float* __restrict__ scale,
                        const float* __restrict__ dhalf, const int* __restrict__ rowtarget,
                        float* __restrict__ out) {
    long gidx = (long)blockIdx.x * blockDim.x + threadIdx.x;
    int row = (int)(gidx >> 10) + 1;   // NC4 == 1024
    int col4 = (int)(gidx & 1023);
    const f4_t* x4 = (const f4_t*)x;
    f4_t* o4 = (f4_t*)out;
    if (row < N_TERMS) {
        f4_t v = x4[(long)row * NC4 + col4];
        f4_t sc = ((const f4_t*)scale)[col4];
        v *= sc;
        __builtin_nontemporal_store(v, &o4[(long)row * NC4 + col4]);
    } else {
        int4 rt = ((const int4*)rowtarget)[col4];
        f4_t dh = ((const f4_t*)dhalf)[col4];
        f4_t v;
        v.x = (rt.x == row) ? dh.x : 0.0f;
        v.y = (rt.y == row) ? dh.y : 0.0f;
        v.z = (rt.z == row) ? dh.z : 0.0f;
        v.w = (rt.w == row) ? dh.w : 0.0f;
        __builtin_nontemporal_store(v, &o4[(long)row * NC4 + col4]);
    }
}

extern "C" void kernel_launch(void* const* d_in, const int* in_sizes, int n_in,
                              void* d_out, int out_size, void* d_ws, size_t ws_size,
                              hipStream_t stream) {
    const float* x = (const float*)d_in[0];
    float* out = (float*)d_out;

    float* ws = (float*)d_ws;
    float* partial   = ws;                       // 128*4096 floats = 2 MB
    float* scale     = partial + NCHUNK * NCOL;  // 4096 floats
    float* dhalf     = scale + NCOL;             // 4096 floats
    int*   crossflag = (int*)(dhalf + NCOL);     // 4096 ints
    int*   rowtarget = crossflag + NCOL;         // 4096 ints
    int*   counter   = rowtarget + NCOL;         // 1 int

    k_partial_abs<<<dim3(NC4 / 256, NCHUNK), 256, 0, stream>>>(x, partial, counter);
    k_stats<<<NCOL / 256, 256, 0, stream>>>(x, partial, out, scale, dhalf,
                                            crossflag, rowtarget, counter);

    const long total4 = (long)(N_TERMS + NCOL - 1) * NC4;  // 6143*1024
    const int blocks = (int)((total4 + 255) / 256);        // 24572 exactly
    k_write<<<blocks, 256, 0, stream>>>(x, scale, dhalf, rowtarget, out);
}

// Round 6
// 137.879 us; speedup vs baseline: 2.9828x; 1.0342x over previous
//
#include <hip/hip_runtime.h>

#define N_TERMS 2048
#define NCOL 4096
#define NC4 1024                           // float4 per row
#define NCHUNK 128
#define RPC (N_TERMS / NCHUNK)             // 16 rows per chunk

typedef float f4_t __attribute__((ext_vector_type(4)));

// ---------------------------------------------------------------------------
// Kernel 1: partial column-wise |x| sums over row chunks (skipping row 0).
// grid (4, 128) = 512 blocks -> 2 blocks/CU, 16 independent float4 loads per
// thread. partial is chunk-major [NCHUNK][NCOL].
// ---------------------------------------------------------------------------
__global__ void k_partial_abs(const float* __restrict__ x, float* __restrict__ partial) {
    int col4 = blockIdx.x * blockDim.x + threadIdx.x;  // [0, 1024)
    int chunk = blockIdx.y;
    int r0 = chunk * RPC;
    int r1 = r0 + RPC;
    if (r0 == 0) r0 = 1;  // center row excluded from abs_sum
    const f4_t* x4 = (const f4_t*)x;
    f4_t acc = {0.f, 0.f, 0.f, 0.f};
#pragma unroll
    for (int r = r0; r < r1; ++r) {
        f4_t v = x4[(long)r * NC4 + col4];
        acc.x += fabsf(v.x);
        acc.y += fabsf(v.y);
        acc.z += fabsf(v.z);
        acc.w += fabsf(v.w);
    }
    ((f4_t*)partial)[chunk * NC4 + col4] = acc;
}

// ---------------------------------------------------------------------------
// Kernel 2: per-column stats. 64 blocks x 256 threads; each block handles 64
// columns with 4 threads/column (each sums 32 of the 128 chunks), combined
// through LDS. 4x the CU coverage and 4x fewer serial load rounds vs the
// 16-block single-thread-per-column version.
// ---------------------------------------------------------------------------
__global__ void k_stats(const float* __restrict__ x, const float* __restrict__ partial,
                        float* __restrict__ out0, float* __restrict__ scale,
                        float* __restrict__ dhalf, int* __restrict__ crossflag) {
    const int t = threadIdx.x;
    const int lane = t & 63;        // column within block's 64-col slice
    const int q = t >> 6;           // which quarter of the 128 chunks
    const int c = blockIdx.x * 64 + lane;

    float s0 = 0.f, s1 = 0.f, s2 = 0.f, s3 = 0.f;
    const int k0 = q * 32;
#pragma unroll 8
    for (int k = 0; k < 32; k += 4) {
        s0 += partial[(k0 + k + 0) * NCOL + c];
        s1 += partial[(k0 + k + 1) * NCOL + c];
        s2 += partial[(k0 + k + 2) * NCOL + c];
        s3 += partial[(k0 + k + 3) * NCOL + c];
    }
    __shared__ float red[4][64];
    red[q][lane] = (s0 + s1) + (s2 + s3);
    __syncthreads();
    if (q == 0) {
        float s = (red[0][lane] + red[1][lane]) + (red[2][lane] + red[3][lane]);
        float x0 = x[c];
        float u = x0 + s;
        float l = x0 - s;
        bool cross = (l * u) < 0.0f;
        bool pos = (l >= 0.0f);
        float denom = u - l;
        float lam = (pos ? 1.0f : 0.0f) +
                    (cross ? ((denom != 0.0f) ? u / denom : 0.5f) : 0.0f);
        float delta = fmaxf(-lam * l, (1.0f - lam) * u);
        float crossf = cross ? 1.0f : 0.0f;
        float posf = pos ? 1.0f : 0.0f;
        out0[c] = (delta * 0.5f + lam * x0) * crossf + x0 * posf;  // output row 0
        scale[c] = lam * crossf + posf;
        dhalf[c] = delta * 0.5f * crossf;
        crossflag[c] = cross ? 1 : 0;
    }
}

// ---------------------------------------------------------------------------
// Kernel 3: exclusive prefix sum of cross flags over 4096 columns -> the tail
// row index each column's new error term lands on. Single block of 256.
// ---------------------------------------------------------------------------
__global__ void k_prefix(const int* __restrict__ crossflag, int* __restrict__ rowtarget) {
    const int T = 256;
    const int PER = NCOL / T;  // 16
    __shared__ int tsum[T];
    int t = threadIdx.x;
    int base = t * PER;
    int ex[PER];
    int run = 0;
#pragma unroll
    for (int i = 0; i < PER; ++i) {
        ex[i] = run;
        run += crossflag[base + i];
    }
    tsum[t] = run;
    __syncthreads();
    for (int off = 1; off < T; off <<= 1) {
        int v = 0;
        if (t >= off) v = tsum[t - off];
        __syncthreads();
        tsum[t] += v;
        __syncthreads();
    }
    int excl = (t == 0) ? 0 : tsum[t - 1];
#pragma unroll
    for (int i = 0; i < PER; ++i) rowtarget[base + i] = N_TERMS + excl + ex[i];
}

// ---------------------------------------------------------------------------
// Kernel 4: write rows 1..6143, 4 rows per thread at a fixed col4.
// Row-groups of 4: group 0 -> rows 1..3 (row 0 already written by k_stats),
// groups 1..511 -> gens rows (x * scale[col]), groups 512..1535 -> tail rows
// (dhalf[col] on the rowtarget[col]==row slot, else 0). 2048 % 4 == 0 so no
// group straddles the gens/tail boundary. Per thread: scale/rt/dh loaded
// once, 4 independent load+store chains, every store 1 KiB coalesced.
// Nontemporal stores: output is never re-read, keep L2 clean for x.
// ---------------------------------------------------------------------------
__global__ void k_write(const float* __restrict__ x, const float* __restrict__ scale,
                        const float* __restrict__ dhalf, const int* __restrict__ rowtarget,
                        float* __restrict__ out) {
    long g = (long)blockIdx.x * blockDim.x + threadIdx.x;  // 1536*1024 threads
    int col4 = (int)(g & 1023);
    int group = (int)(g >> 10);       // [0, 1536)
    int r0 = group << 2;
    const f4_t* x4 = (const f4_t*)x;
    f4_t* o4 = (f4_t*)out;

    if (group < 512) {
        f4_t sc = ((const f4_t*)scale)[col4];
        if (group == 0) {
#pragma unroll
            for (int r = 1; r < 4; ++r) {
                f4_t v = x4[(long)r * NC4 + col4] * sc;
                __builtin_nontemporal_store(v, &o4[(long)r * NC4 + col4]);
            }
        } else {
#pragma unroll
            for (int i = 0; i < 4; ++i) {
                int r = r0 + i;
                f4_t v = x4[(long)r * NC4 + col4] * sc;
                __builtin_nontemporal_store(v, &o4[(long)r * NC4 + col4]);
            }
        }
    } else {
        int4 rt = ((const int4*)rowtarget)[col4];
        f4_t dh = ((const f4_t*)dhalf)[col4];
#pragma unroll
        for (int i = 0; i < 4; ++i) {
            int r = r0 + i;
            f4_t v;
            v.x = (rt.x == r) ? dh.x : 0.0f;
            v.y = (rt.y == r) ? dh.y : 0.0f;
            v.z = (rt.z == r) ? dh.z : 0.0f;
            v.w = (rt.w == r) ? dh.w : 0.0f;
            __builtin_nontemporal_store(v, &o4[(long)r * NC4 + col4]);
        }
    }
}

extern "C" void kernel_launch(void* const* d_in, const int* in_sizes, int n_in,
                              void* d_out, int out_size, void* d_ws, size_t ws_size,
                              hipStream_t stream) {
    const float* x = (const float*)d_in[0];
    float* out = (float*)d_out;

    float* ws = (float*)d_ws;
    float* partial   = ws;                       // 128*4096 floats = 2 MB
    float* scale     = partial + NCHUNK * NCOL;  // 4096 floats
    float* dhalf     = scale + NCOL;             // 4096 floats
    int*   crossflag = (int*)(dhalf + NCOL);     // 4096 ints
    int*   rowtarget = crossflag + NCOL;         // 4096 ints

    k_partial_abs<<<dim3(NC4 / 256, NCHUNK), 256, 0, stream>>>(x, partial);
    k_stats<<<64, 256, 0, stream>>>(x, partial, out, scale, dhalf, crossflag);
    k_prefix<<<1, 256, 0, stream>>>(crossflag, rowtarget);

    const int blocks = 1536 * 1024 / 256;  // 6144 blocks, 4 rows/thread
    k_write<<<blocks, 256, 0, stream>>>(x, scale, dhalf, rowtarget, out);
}